// Round 2
// baseline (284.981 us; speedup 1.0000x reference)
//
#include <hip/hip_runtime.h>
#include <hip/hip_bf16.h>

// FlatConv3x3NNUE: 25 per-position conv towers (2x2,2x2,1x1,1x1) + clip-sum + NNUE head.
// R2: 4-wave blocks, phase-locked on same position -> B-fragments hit L1 (L2 traffic /4).
// Single aliased inter-layer LDS buffer per wave (30KB/block).

#define NPOS 25
#define BATCH 8192
#define CMAXF 0.9921875f
#define NGRP 5
#define PPG 5

// ws layout in bf16 elements
#define W1F_OFF 0           // [25][32][64][8]   (K=18->32 padded, N=512 = 4 spatial x 128)
#define W2F_OFF 409600      // [25][8][16][64][8] (K=512, N=128)
#define W3F_OFF 2048000     // [25][8][4][64][8]  (K=128, N=128)
#define W4F_OFF 2457600     // [25][2][4][64][8]  (K=128, N=32)
#define WF_TOTAL 2560000
#define PART_BYTE_OFF 5120000  // float [5][8192][32] partial features

using bf16x8 = __attribute__((ext_vector_type(8))) short;
using f32x4  = __attribute__((ext_vector_type(4))) float;

__device__ __forceinline__ unsigned short f2bf(float f) {
  union { float f; unsigned u; } v; v.f = f;
  unsigned u = v.u + 0x7fffu + ((v.u >> 16) & 1u);   // RNE
  return (unsigned short)(u >> 16);
}

__device__ __forceinline__ f32x4 mfma16(bf16x8 a, bf16x8 b, f32x4 c) {
  return __builtin_amdgcn_mfma_f32_16x16x32_bf16(a, b, c, 0, 0, 0);
}

// ---------------- prep: weights -> bf16 fragment-linear ----------------
__global__ __launch_bounds__(256) void prep_kernel(
    const float* __restrict__ W1, const float* __restrict__ W2,
    const float* __restrict__ W3, const float* __restrict__ W4,
    unsigned short* __restrict__ wf)
{
  int idx = blockIdx.x * 256 + threadIdx.x;
  if (idx >= WF_TOTAL) return;
  float val = 0.f;
  if (idx < W2F_OFF) {              // W1e: K=18 (c*9+py*3+px), padded to 32; N=512 (s*128+o)
    int e = idx; int j = e & 7; int l = (e >> 3) & 63; int nt = (e >> 9) & 31; int p = e >> 14;
    int k = (l >> 4) * 8 + j;
    int n = nt * 16 + (l & 15);
    int s = n >> 7, o = n & 127;
    int si = s >> 1, sj = s & 1;
    if (k < 18) {
      int c = (k >= 9) ? 1 : 0;
      int rr = k - c * 9;
      int py = rr / 3, px = rr - (rr / 3) * 3;
      int di = py - si, dj = px - sj;
      if (di >= 0 && di < 2 && dj >= 0 && dj < 2)
        val = W1[((p * 128 + o) * 2 + c) * 4 + di * 2 + dj];
    }
  } else if (idx < W3F_OFF) {       // W2: k2 = s*128 + c
    int e = idx - W2F_OFF; int j = e & 7; int l = (e >> 3) & 63;
    int kq = (e >> 9) & 15; int nt = (e >> 13) & 7; int p = e >> 16;
    int k2 = kq * 32 + (l >> 4) * 8 + j;
    int o = nt * 16 + (l & 15);
    int s = k2 >> 7, c = k2 & 127;
    val = W2[((p * 128 + o) * 128 + c) * 4 + s];
  } else if (idx < W4F_OFF) {       // W3[o][c]
    int e = idx - W3F_OFF; int j = e & 7; int l = (e >> 3) & 63;
    int kq = (e >> 9) & 3; int nt = (e >> 11) & 7; int p = e >> 14;
    int k = kq * 32 + (l >> 4) * 8 + j;
    int o = nt * 16 + (l & 15);
    val = W3[(p * 128 + o) * 128 + k];
  } else {                          // W4[o][c]
    int e = idx - W4F_OFF; int j = e & 7; int l = (e >> 3) & 63;
    int kq = (e >> 9) & 3; int nt = (e >> 11) & 1; int p = e >> 12;
    int k = kq * 32 + (l >> 4) * 8 + j;
    int o = nt * 16 + (l & 15);
    val = W4[(p * 32 + o) * 128 + k];
  }
  wf[idx] = f2bf(val);
}

// ---------------- tower: 4 waves/block, phase-locked, 64 rows/block ----------------
__global__ __launch_bounds__(256) void tower_kernel(
    const float* __restrict__ x,
    const float* __restrict__ b1v, const float* __restrict__ b2v,
    const float* __restrict__ b3v, const float* __restrict__ b4v,
    const unsigned short* __restrict__ wf, float* __restrict__ part)
{
  __shared__ __align__(16) unsigned short xs[4][16 * 104];   // [wave][row][c*52+pix]
  __shared__ __align__(16) unsigned short hb[4][16 * 128];   // aliased inter-layer buffer

  const int l = threadIdx.x & 63;
  const int wv = threadIdx.x >> 6;
  const int l15 = l & 15;
  const int g = l >> 4;

  // XCD-aware remap: 640 blocks -> each XCD gets a contiguous chunk of (grp, btile)
  int bid = blockIdx.x;
  int lin = (bid & 7) * 80 + (bid >> 3);
  int grp = lin / 128;
  int btile = lin - grp * 128;
  const int R0 = btile * 64 + wv * 16;   // this wave's 16 rows

  unsigned short* xsw = xs[wv];
  unsigned short* hbw = hb[wv];

  for (int idx = l; idx < 16 * 98; idx += 64) {
    int r = idx / 98;
    int q = idx - r * 98;
    int c = q / 49;
    int pix = q - c * 49;
    xsw[r * 104 + c * 52 + pix] = f2bf(x[(R0 + r) * 98 + q]);
  }

  // per-lane K-slot decode for the L1 fragment (fixed per lane)
  int kbase[8]; bool kreal[8];
#pragma unroll
  for (int j = 0; j < 8; ++j) {
    int k = g * 8 + j;
    if (k < 18) {
      int c = (k >= 9) ? 1 : 0;
      int rr = k - c * 9;
      int py = rr / 3, px = rr - (rr / 3) * 3;
      kbase[j] = c * 52 + py * 7 + px;
      kreal[j] = true;
    } else { kbase[j] = 0; kreal[j] = false; }
  }

  const f32x4 zf = {0.f, 0.f, 0.f, 0.f};
  f32x4 facc0 = zf, facc1 = zf;
  __syncthreads();

  for (int pp = 0; pp < PPG; ++pp) {
    const int p = grp * PPG + pp;
    const int y0 = p / 5;
    const int x0 = p - y0 * 5;
    const int poff = y0 * 7 + x0;

    bf16x8 a1;
#pragma unroll
    for (int j = 0; j < 8; ++j) {
      unsigned short v = kreal[j] ? xsw[l15 * 104 + kbase[j] + poff] : (unsigned short)0;
      a1[j] = (short)v;
    }

    float bias1[8];
#pragma unroll
    for (int t = 0; t < 8; ++t) bias1[t] = b1v[p * 128 + t * 16 + l15];

    f32x4 acc2[8];
#pragma unroll
    for (int t = 0; t < 8; ++t) acc2[t] = zf;

    const unsigned short* w1p = wf + W1F_OFF + (p * 32) * 512 + l * 8;
    const unsigned short* w2p = wf + W2F_OFF + (p * 8) * 16 * 512 + l * 8;

    for (int s = 0; s < 4; ++s) {
      // L1 (this spatial): 8 n-tiles, K=32 (18 real)
#pragma unroll
      for (int t = 0; t < 8; ++t) {
        bf16x8 bw = *(const bf16x8*)(w1p + (s * 8 + t) * 512);
        f32x4 c1 = mfma16(a1, bw, zf);
#pragma unroll
        for (int r = 0; r < 4; ++r) {
          int row = g * 4 + r;
          float v = c1[r] + bias1[t];
          v = v > 0.f ? v : 0.f;
          hbw[(row * 128 + (t * 16 + l15)) ^ ((row & 7) << 3)] = f2bf(v);
        }
      }
      __syncthreads();
      // L2 partial over this spatial's 128 input channels
#pragma unroll
      for (int kq = 0; kq < 4; ++kq) {
        bf16x8 a2 = *(const bf16x8*)&hbw[(l15 * 128 + (kq * 32 + g * 8)) ^ ((l15 & 7) << 3)];
#pragma unroll
        for (int t = 0; t < 8; ++t) {
          bf16x8 bw = *(const bf16x8*)(w2p + (t * 16 + (s * 4 + kq)) * 512);
          acc2[t] = mfma16(a2, bw, acc2[t]);
        }
      }
      __syncthreads();
    }

    // L2 epilogue -> h2 (reuse hbw; last reads of hbw were before the trailing barrier)
#pragma unroll
    for (int t = 0; t < 8; ++t) {
      float bias = b2v[p * 128 + t * 16 + l15];
#pragma unroll
      for (int r = 0; r < 4; ++r) {
        int row = g * 4 + r;
        float v = acc2[t][r] + bias;
        v = v > 0.f ? v : 0.f;
        hbw[(row * 128 + (t * 16 + l15)) ^ ((row & 7) << 3)] = f2bf(v);
      }
    }
    __syncthreads();

    // L3
    f32x4 acc3[8];
#pragma unroll
    for (int t = 0; t < 8; ++t) acc3[t] = zf;
    const unsigned short* w3p = wf + W3F_OFF + (p * 8) * 4 * 512 + l * 8;
#pragma unroll
    for (int kq = 0; kq < 4; ++kq) {
      bf16x8 a = *(const bf16x8*)&hbw[(l15 * 128 + (kq * 32 + g * 8)) ^ ((l15 & 7) << 3)];
#pragma unroll
      for (int t = 0; t < 8; ++t) {
        bf16x8 bw = *(const bf16x8*)(w3p + (t * 4 + kq) * 512);
        acc3[t] = mfma16(a, bw, acc3[t]);
      }
    }
    __syncthreads();   // reads of h2 done before overwriting with h3
#pragma unroll
    for (int t = 0; t < 8; ++t) {
      float bias = b3v[p * 128 + t * 16 + l15];
#pragma unroll
      for (int r = 0; r < 4; ++r) {
        int row = g * 4 + r;
        float v = acc3[t][r] + bias;
        v = v > 0.f ? v : 0.f;
        hbw[(row * 128 + (t * 16 + l15)) ^ ((row & 7) << 3)] = f2bf(v);
      }
    }
    __syncthreads();

    // L4 + clamp + accumulate feature (fp32, in regs)
    f32x4 c40 = zf, c41 = zf;
    const unsigned short* w4p = wf + W4F_OFF + (p * 2) * 4 * 512 + l * 8;
#pragma unroll
    for (int kq = 0; kq < 4; ++kq) {
      bf16x8 a = *(const bf16x8*)&hbw[(l15 * 128 + (kq * 32 + g * 8)) ^ ((l15 & 7) << 3)];
      bf16x8 bw0 = *(const bf16x8*)(w4p + (0 * 4 + kq) * 512);
      bf16x8 bw1 = *(const bf16x8*)(w4p + (1 * 4 + kq) * 512);
      c40 = mfma16(a, bw0, c40);
      c41 = mfma16(a, bw1, c41);
    }
    __syncthreads();   // h3 reads done before next position overwrites hbw
    {
      float bias0 = b4v[p * 32 + l15];
      float bias1b = b4v[p * 32 + 16 + l15];
#pragma unroll
      for (int r = 0; r < 4; ++r) {
        float v0 = c40[r] + bias0;
        v0 = v0 < -1.f ? -1.f : (v0 > CMAXF ? CMAXF : v0);
        facc0[r] += v0;
        float v1 = c41[r] + bias1b;
        v1 = v1 < -1.f ? -1.f : (v1 > CMAXF ? CMAXF : v1);
        facc1[r] += v1;
      }
    }
  }

#pragma unroll
  for (int r = 0; r < 4; ++r) {
    int row = R0 + g * 4 + r;
    part[(grp * BATCH + row) * 32 + l15] = facc0[r];
    part[(grp * BATCH + row) * 32 + 16 + l15] = facc1[r];
  }
}

// ---------------- head: reduce partials + clipped MLP ----------------
__global__ __launch_bounds__(256) void head_kernel(
    const float* __restrict__ part,
    const float* __restrict__ fc1w, const float* __restrict__ fc1b,
    const float* __restrict__ fc2w, const float* __restrict__ fc2b,
    const float* __restrict__ fc3w, const float* __restrict__ fc3b,
    float* __restrict__ out)
{
  int r = blockIdx.x * 256 + threadIdx.x;
  float feat[32];
#pragma unroll
  for (int i = 0; i < 32; ++i) feat[i] = 0.f;
#pragma unroll
  for (int gi = 0; gi < NGRP; ++gi) {
    const float4* pr = (const float4*)(part + ((size_t)gi * BATCH + r) * 32);
#pragma unroll
    for (int q = 0; q < 8; ++q) {
      float4 v = pr[q];
      feat[q * 4 + 0] += v.x; feat[q * 4 + 1] += v.y;
      feat[q * 4 + 2] += v.z; feat[q * 4 + 3] += v.w;
    }
  }
#pragma unroll
  for (int i = 0; i < 32; ++i) {
    float v = feat[i];
    feat[i] = v < 0.f ? 0.f : (v > CMAXF ? CMAXF : v);
  }
  float v1[32];
  for (int o = 0; o < 32; ++o) {
    float a = fc1b[o];
    for (int k = 0; k < 32; ++k) a += feat[k] * fc1w[o * 32 + k];
    v1[o] = a < 0.f ? 0.f : (a > CMAXF ? CMAXF : a);
  }
  float v2[32];
  for (int o = 0; o < 32; ++o) {
    float a = fc2b[o];
    for (int k = 0; k < 32; ++k) a += v1[k] * fc2w[o * 32 + k];
    v2[o] = a < 0.f ? 0.f : (a > CMAXF ? CMAXF : a);
  }
  float a = fc3b[0];
  for (int k = 0; k < 32; ++k) a += v2[k] * fc3w[k];
  out[r] = a;
}

extern "C" void kernel_launch(void* const* d_in, const int* in_sizes, int n_in,
                              void* d_out, int out_size, void* d_ws, size_t ws_size,
                              hipStream_t stream) {
  const float* x    = (const float*)d_in[0];
  const float* W1   = (const float*)d_in[1];
  const float* b1   = (const float*)d_in[2];
  const float* W2   = (const float*)d_in[3];
  const float* b2   = (const float*)d_in[4];
  const float* W3   = (const float*)d_in[5];
  const float* b3   = (const float*)d_in[6];
  const float* W4   = (const float*)d_in[7];
  const float* b4   = (const float*)d_in[8];
  const float* fc1w = (const float*)d_in[9];
  const float* fc1b = (const float*)d_in[10];
  const float* fc2w = (const float*)d_in[11];
  const float* fc2b = (const float*)d_in[12];
  const float* fc3w = (const float*)d_in[13];
  const float* fc3b = (const float*)d_in[14];
  float* out = (float*)d_out;

  unsigned short* wf = (unsigned short*)d_ws;
  float* part = (float*)((char*)d_ws + PART_BYTE_OFF);

  prep_kernel<<<(WF_TOTAL + 255) / 256, 256, 0, stream>>>(W1, W2, W3, W4, wf);
  tower_kernel<<<640, 256, 0, stream>>>(x, b1, b2, b3, b4, wf, part);
  head_kernel<<<BATCH / 256, 256, 0, stream>>>(part, fc1w, fc1b, fc2w, fc2b, fc3w, fc3b, out);
}

// Round 3
// 141.344 us; speedup vs baseline: 2.0162x; 2.0162x over previous
//
#include <hip/hip_runtime.h>
#include <hip/hip_bf16.h>

// FlatConv3x3NNUE R3: 4-wave blocks share B-fragments via LDS double-buffer with
// global_load_lds prefetch (T3-lite 2-phase pipeline). 25 uniform 8KB phases/position.

#define NPOS 25
#define BATCH 8192
#define CMAXF 0.9921875f
#define NGRP 5
#define PPG 5

// ws layout in bf16 elements
#define W1F_OFF 0           // [25][32 nt][64][8]   nt = s*8+t (K=18->32, N=512)
#define W2F_OFF 409600      // [25][8 t][16 sk][64][8]  sk = s*4+kq
#define W3F_OFF 2048000     // [25][8 t][4 kq][64][8]
#define W4F_OFF 2457600     // [25][2 nt][4 kq][64][8]
#define WF_TOTAL 2560000
#define PART_BYTE_OFF 5120000  // float [5][8192][32]

using bf16x8 = __attribute__((ext_vector_type(8))) short;
using f32x4  = __attribute__((ext_vector_type(4))) float;

__device__ __forceinline__ unsigned short f2bf(float f) {
  union { float f; unsigned u; } v; v.f = f;
  unsigned u = v.u + 0x7fffu + ((v.u >> 16) & 1u);   // RNE
  return (unsigned short)(u >> 16);
}

__device__ __forceinline__ f32x4 mfma16(bf16x8 a, bf16x8 b, f32x4 c) {
  return __builtin_amdgcn_mfma_f32_16x16x32_bf16(a, b, c, 0, 0, 0);
}

__device__ __forceinline__ void gload_lds16(const unsigned short* g, unsigned short* l) {
  __builtin_amdgcn_global_load_lds(
      (const __attribute__((address_space(1))) unsigned int*)g,
      (__attribute__((address_space(3))) unsigned int*)l, 16, 0, 0);
}

// ---------------- prep: weights -> bf16 fragment-linear ----------------
__global__ __launch_bounds__(256) void prep_kernel(
    const float* __restrict__ W1, const float* __restrict__ W2,
    const float* __restrict__ W3, const float* __restrict__ W4,
    unsigned short* __restrict__ wf)
{
  int idx = blockIdx.x * 256 + threadIdx.x;
  if (idx >= WF_TOTAL) return;
  float val = 0.f;
  if (idx < W2F_OFF) {              // W1e
    int e = idx; int j = e & 7; int l = (e >> 3) & 63; int nt = (e >> 9) & 31; int p = e >> 14;
    int k = (l >> 4) * 8 + j;
    int n = nt * 16 + (l & 15);
    int s = n >> 7, o = n & 127;
    int si = s >> 1, sj = s & 1;
    if (k < 18) {
      int c = (k >= 9) ? 1 : 0;
      int rr = k - c * 9;
      int py = rr / 3, px = rr - (rr / 3) * 3;
      int di = py - si, dj = px - sj;
      if (di >= 0 && di < 2 && dj >= 0 && dj < 2)
        val = W1[((p * 128 + o) * 2 + c) * 4 + di * 2 + dj];
    }
  } else if (idx < W3F_OFF) {       // W2
    int e = idx - W2F_OFF; int j = e & 7; int l = (e >> 3) & 63;
    int kq = (e >> 9) & 15; int nt = (e >> 13) & 7; int p = e >> 16;
    int k2 = kq * 32 + (l >> 4) * 8 + j;
    int o = nt * 16 + (l & 15);
    int s = k2 >> 7, c = k2 & 127;
    val = W2[((p * 128 + o) * 128 + c) * 4 + s];
  } else if (idx < W4F_OFF) {       // W3
    int e = idx - W3F_OFF; int j = e & 7; int l = (e >> 3) & 63;
    int kq = (e >> 9) & 3; int nt = (e >> 11) & 7; int p = e >> 14;
    int k = kq * 32 + (l >> 4) * 8 + j;
    int o = nt * 16 + (l & 15);
    val = W3[(p * 128 + o) * 128 + k];
  } else {                          // W4
    int e = idx - W4F_OFF; int j = e & 7; int l = (e >> 3) & 63;
    int kq = (e >> 9) & 3; int nt = (e >> 11) & 1; int p = e >> 12;
    int k = kq * 32 + (l >> 4) * 8 + j;
    int o = nt * 16 + (l & 15);
    val = W4[(p * 32 + o) * 128 + k];
  }
  wf[idx] = f2bf(val);
}

// phase q (0..24) -> frag f source element offset (within wf) for position p
__device__ __forceinline__ int frag_src(int p, int q, int f) {
  if (q < 20) {
    int s = q / 5, rem = q - s * 5;
    if (rem == 0) return W1F_OFF + (p * 32 + s * 8 + f) * 512;          // L1(s), f=t
    int kq = rem - 1;
    return W2F_OFF + ((p * 8 + f) * 16 + s * 4 + kq) * 512;             // L2(s,kq), f=t
  } else if (q < 24) {
    int kq = q - 20;
    return W3F_OFF + ((p * 8 + f) * 4 + kq) * 512;                      // L3(kq), f=t
  }
  return W4F_OFF + ((p * 2 + (f >> 2)) * 4 + (f & 3)) * 512;            // L4, f=nt*4+kq
}

// ---------------- tower: 4 waves/block, LDS B-staging, 2-phase pipeline ----------------
__global__ __launch_bounds__(256, 3) void tower_kernel(
    const float* __restrict__ x,
    const float* __restrict__ b1v, const float* __restrict__ b2v,
    const float* __restrict__ b3v, const float* __restrict__ b4v,
    const unsigned short* __restrict__ wf, float* __restrict__ part)
{
  __shared__ __align__(16) unsigned short ldsB[2 * 8 * 512];            // 16KB B double-buffer
  __shared__ __align__(16) unsigned short xs[4][16 * 104];
  __shared__ __align__(16) unsigned short hb[4][16 * 128];

  const int l = threadIdx.x & 63;
  const int wv = threadIdx.x >> 6;
  const int l15 = l & 15;
  const int g = l >> 4;

  // XCD-aware bijective remap: 640 blocks, 80/XCD contiguous
  int bid = blockIdx.x;
  int lin = (bid & 7) * 80 + (bid >> 3);
  int grp = lin / 128;
  int btile = lin - grp * 128;
  const int R0 = btile * 64 + wv * 16;

  unsigned short* xsw = xs[wv];
  unsigned short* hbw = hb[wv];

  for (int idx = l; idx < 16 * 98; idx += 64) {
    int r = idx / 98;
    int q = idx - r * 98;
    int c = q / 49;
    int pix = q - c * 49;
    xsw[r * 104 + c * 52 + pix] = f2bf(x[(R0 + r) * 98 + q]);
  }

  int kbase[8]; bool kreal[8];
#pragma unroll
  for (int j = 0; j < 8; ++j) {
    int k = g * 8 + j;
    if (k < 18) {
      int c = (k >= 9) ? 1 : 0;
      int rr = k - c * 9;
      int py = rr / 3, px = rr - (rr / 3) * 3;
      kbase[j] = c * 52 + py * 7 + px;
      kreal[j] = true;
    } else { kbase[j] = 0; kreal[j] = false; }
  }

  const f32x4 zf = {0.f, 0.f, 0.f, 0.f};
  f32x4 facc0 = zf, facc1 = zf;

  // prologue: stage (first position, phase 0) into buf 0
  {
    int p0 = grp * PPG;
#pragma unroll
    for (int h = 0; h < 2; ++h) {
      int f = wv + h * 4;
      gload_lds16(wf + frag_src(p0, 0, f) + l * 8, ldsB + f * 512);
    }
  }
  __syncthreads();

  int cur = 0;

#define STAGE(pn, qn)                                                        \
  {                                                                          \
    unsigned short* dstb = ldsB + (cur ^ 1) * 4096;                          \
    _Pragma("unroll")                                                        \
    for (int h2_ = 0; h2_ < 2; ++h2_) {                                      \
      int f_ = wv + h2_ * 4;                                                 \
      gload_lds16(wf + frag_src((pn), (qn), f_) + l * 8, dstb + f_ * 512);   \
    }                                                                        \
  }

  for (int pp = 0; pp < PPG; ++pp) {
    const int p = grp * PPG + pp;
    const int y0 = p / 5;
    const int x0 = p - y0 * 5;
    const int poff = y0 * 7 + x0;

    bf16x8 a1;
#pragma unroll
    for (int j = 0; j < 8; ++j) {
      unsigned short v = kreal[j] ? xsw[l15 * 104 + kbase[j] + poff] : (unsigned short)0;
      a1[j] = (short)v;
    }

    float bias1[8];
#pragma unroll
    for (int t = 0; t < 8; ++t) bias1[t] = b1v[p * 128 + t * 16 + l15];

    f32x4 acc2[8];
#pragma unroll
    for (int t = 0; t < 8; ++t) acc2[t] = zf;

    for (int s = 0; s < 4; ++s) {
      // ---- phase q=5s : L1(s) ----
      STAGE(p, 5 * s + 1);
      {
        const unsigned short* bbuf = ldsB + cur * 4096;
        f32x4 c1[8];
#pragma unroll
        for (int t = 0; t < 8; ++t) {
          bf16x8 bw = *(const bf16x8*)(bbuf + t * 512 + l * 8);
          c1[t] = mfma16(a1, bw, zf);
        }
#pragma unroll
        for (int t = 0; t < 8; ++t) {
#pragma unroll
          for (int r = 0; r < 4; ++r) {
            int row = g * 4 + r;
            float v = c1[t][r] + bias1[t];
            v = v > 0.f ? v : 0.f;
            hbw[(row * 128 + (t * 16 + l15)) ^ ((row & 7) << 3)] = f2bf(v);
          }
        }
      }
      __syncthreads(); cur ^= 1;

      // ---- phases q=5s+1..5s+4 : L2(s, kq) ----
      for (int kq = 0; kq < 4; ++kq) {
        int q = 5 * s + 1 + kq;
        if (q < 19) { STAGE(p, q + 1); }
        else       { STAGE(p, 20); }           // q==19 -> stage L3 kq=0
        {
          const unsigned short* bbuf = ldsB + cur * 4096;
          bf16x8 a2 = *(const bf16x8*)&hbw[(l15 * 128 + (kq * 32 + g * 8)) ^ ((l15 & 7) << 3)];
#pragma unroll
          for (int t = 0; t < 8; ++t) {
            bf16x8 bw = *(const bf16x8*)(bbuf + t * 512 + l * 8);
            acc2[t] = mfma16(a2, bw, acc2[t]);
          }
          if (s == 3 && kq == 3) {
            // L2 epilogue -> h2 (into hbw; own-wave ds_read data already consumed)
#pragma unroll
            for (int t = 0; t < 8; ++t) {
              float bias = b2v[p * 128 + t * 16 + l15];
#pragma unroll
              for (int r = 0; r < 4; ++r) {
                int row = g * 4 + r;
                float v = acc2[t][r] + bias;
                v = v > 0.f ? v : 0.f;
                hbw[(row * 128 + (t * 16 + l15)) ^ ((row & 7) << 3)] = f2bf(v);
              }
            }
          }
        }
        __syncthreads(); cur ^= 1;
      }
    }

    // ---- phases q=20..23 : L3(kq) ----
    f32x4 acc3[8];
#pragma unroll
    for (int t = 0; t < 8; ++t) acc3[t] = zf;
    for (int kq = 0; kq < 4; ++kq) {
      STAGE(p, 21 + kq);   // kq==3 stages q=24 (L4)
      {
        const unsigned short* bbuf = ldsB + cur * 4096;
        bf16x8 a = *(const bf16x8*)&hbw[(l15 * 128 + (kq * 32 + g * 8)) ^ ((l15 & 7) << 3)];
#pragma unroll
        for (int t = 0; t < 8; ++t) {
          bf16x8 bw = *(const bf16x8*)(bbuf + t * 512 + l * 8);
          acc3[t] = mfma16(a, bw, acc3[t]);
        }
        if (kq == 3) {
#pragma unroll
          for (int t = 0; t < 8; ++t) {
            float bias = b3v[p * 128 + t * 16 + l15];
#pragma unroll
            for (int r = 0; r < 4; ++r) {
              int row = g * 4 + r;
              float v = acc3[t][r] + bias;
              v = v > 0.f ? v : 0.f;
              hbw[(row * 128 + (t * 16 + l15)) ^ ((row & 7) << 3)] = f2bf(v);
            }
          }
        }
      }
      __syncthreads(); cur ^= 1;
    }

    // ---- phase q=24 : L4 ----
    if (pp != PPG - 1) { STAGE(p + 1, 0); }
    {
      const unsigned short* bbuf = ldsB + cur * 4096;
      f32x4 c40 = zf, c41 = zf;
#pragma unroll
      for (int kq = 0; kq < 4; ++kq) {
        bf16x8 a = *(const bf16x8*)&hbw[(l15 * 128 + (kq * 32 + g * 8)) ^ ((l15 & 7) << 3)];
        bf16x8 bw0 = *(const bf16x8*)(bbuf + kq * 512 + l * 8);
        bf16x8 bw1 = *(const bf16x8*)(bbuf + (4 + kq) * 512 + l * 8);
        c40 = mfma16(a, bw0, c40);
        c41 = mfma16(a, bw1, c41);
      }
      float bias0 = b4v[p * 32 + l15];
      float bias1b = b4v[p * 32 + 16 + l15];
#pragma unroll
      for (int r = 0; r < 4; ++r) {
        float v0 = c40[r] + bias0;
        v0 = v0 < -1.f ? -1.f : (v0 > CMAXF ? CMAXF : v0);
        facc0[r] += v0;
        float v1 = c41[r] + bias1b;
        v1 = v1 < -1.f ? -1.f : (v1 > CMAXF ? CMAXF : v1);
        facc1[r] += v1;
      }
    }
    __syncthreads(); cur ^= 1;
  }
#undef STAGE

#pragma unroll
  for (int r = 0; r < 4; ++r) {
    int row = R0 + g * 4 + r;
    part[(grp * BATCH + row) * 32 + l15] = facc0[r];
    part[(grp * BATCH + row) * 32 + 16 + l15] = facc1[r];
  }
}

// ---------------- head: reduce partials + clipped MLP ----------------
__global__ __launch_bounds__(256) void head_kernel(
    const float* __restrict__ part,
    const float* __restrict__ fc1w, const float* __restrict__ fc1b,
    const float* __restrict__ fc2w, const float* __restrict__ fc2b,
    const float* __restrict__ fc3w, const float* __restrict__ fc3b,
    float* __restrict__ out)
{
  int r = blockIdx.x * 256 + threadIdx.x;
  float feat[32];
#pragma unroll
  for (int i = 0; i < 32; ++i) feat[i] = 0.f;
#pragma unroll
  for (int gi = 0; gi < NGRP; ++gi) {
    const float4* pr = (const float4*)(part + ((size_t)gi * BATCH + r) * 32);
#pragma unroll
    for (int q = 0; q < 8; ++q) {
      float4 v = pr[q];
      feat[q * 4 + 0] += v.x; feat[q * 4 + 1] += v.y;
      feat[q * 4 + 2] += v.z; feat[q * 4 + 3] += v.w;
    }
  }
#pragma unroll
  for (int i = 0; i < 32; ++i) {
    float v = feat[i];
    feat[i] = v < 0.f ? 0.f : (v > CMAXF ? CMAXF : v);
  }
  float v1[32];
  for (int o = 0; o < 32; ++o) {
    float a = fc1b[o];
    for (int k = 0; k < 32; ++k) a += feat[k] * fc1w[o * 32 + k];
    v1[o] = a < 0.f ? 0.f : (a > CMAXF ? CMAXF : a);
  }
  float v2[32];
  for (int o = 0; o < 32; ++o) {
    float a = fc2b[o];
    for (int k = 0; k < 32; ++k) a += v1[k] * fc2w[o * 32 + k];
    v2[o] = a < 0.f ? 0.f : (a > CMAXF ? CMAXF : a);
  }
  float a = fc3b[0];
  for (int k = 0; k < 32; ++k) a += v2[k] * fc3w[k];
  out[r] = a;
}

extern "C" void kernel_launch(void* const* d_in, const int* in_sizes, int n_in,
                              void* d_out, int out_size, void* d_ws, size_t ws_size,
                              hipStream_t stream) {
  const float* x    = (const float*)d_in[0];
  const float* W1   = (const float*)d_in[1];
  const float* b1   = (const float*)d_in[2];
  const float* W2   = (const float*)d_in[3];
  const float* b2   = (const float*)d_in[4];
  const float* W3   = (const float*)d_in[5];
  const float* b3   = (const float*)d_in[6];
  const float* W4   = (const float*)d_in[7];
  const float* b4   = (const float*)d_in[8];
  const float* fc1w = (const float*)d_in[9];
  const float* fc1b = (const float*)d_in[10];
  const float* fc2w = (const float*)d_in[11];
  const float* fc2b = (const float*)d_in[12];
  const float* fc3w = (const float*)d_in[13];
  const float* fc3b = (const float*)d_in[14];
  float* out = (float*)d_out;

  unsigned short* wf = (unsigned short*)d_ws;
  float* part = (float*)((char*)d_ws + PART_BYTE_OFF);

  prep_kernel<<<(WF_TOTAL + 255) / 256, 256, 0, stream>>>(W1, W2, W3, W4, wf);
  tower_kernel<<<640, 256, 0, stream>>>(x, b1, b2, b3, b4, wf, part);
  head_kernel<<<BATCH / 256, 256, 0, stream>>>(part, fc1w, fc1b, fc2w, fc2b, fc3w, fc3b, out);
}

// Round 4
// 111.680 us; speedup vs baseline: 2.5518x; 1.2656x over previous
//
#include <hip/hip_runtime.h>
#include <hip/hip_bf16.h>

// FlatConv3x3NNUE R4: counted-vmcnt 3-buffer phase pipeline (T4), uniform [p][q][frag]
// weight layout, b1 folded into W1 (k=18, const-1 activation), cvt_pk epilogues,
// setprio around MFMA clusters, parallel head.

#define NPOS 25
#define BATCH 8192
#define CMAXF 0.9921875f
#define NGRP 5
#define PPG 5

// wf: bf16 [25 p][25 q][8 f][64 lane][8 j]  (8KB per phase, contiguous)
#define WF_TOTAL 2560000
#define PART_BYTE_OFF 5120000  // float [5][8192][32]

using bf16x8 = __attribute__((ext_vector_type(8))) short;
using f32x4  = __attribute__((ext_vector_type(4))) float;

__device__ __forceinline__ unsigned short f2bf(float f) {
  union { float f; unsigned u; } v; v.f = f;
  unsigned u = v.u + 0x7fffu + ((v.u >> 16) & 1u);   // RNE
  return (unsigned short)(u >> 16);
}

__device__ __forceinline__ f32x4 mfma16(bf16x8 a, bf16x8 b, f32x4 c) {
  return __builtin_amdgcn_mfma_f32_16x16x32_bf16(a, b, c, 0, 0, 0);
}

__device__ __forceinline__ void gload_lds16(const unsigned short* g, unsigned short* l) {
  __builtin_amdgcn_global_load_lds(
      (const __attribute__((address_space(1))) unsigned int*)g,
      (__attribute__((address_space(3))) unsigned int*)l, 16, 0, 0);
}

// ---------------- prep: weights -> bf16 [p][q][f][lane][j], b1 folded at k=18 ----------
__global__ __launch_bounds__(256) void prep_kernel(
    const float* __restrict__ W1, const float* __restrict__ b1,
    const float* __restrict__ W2, const float* __restrict__ W3,
    const float* __restrict__ W4, unsigned short* __restrict__ wf)
{
  int idx = blockIdx.x * 256 + threadIdx.x;
  if (idx >= WF_TOTAL) return;
  int j = idx & 7;
  int l = (idx >> 3) & 63;
  int f = (idx >> 9) & 7;
  int pq = idx >> 12;            // p*25+q
  int p = pq / 25, q = pq - p * 25;
  int kk = ((l >> 4) << 3) + j;  // 0..31
  int l15 = l & 15;
  float val = 0.f;
  if (q < 20) {
    int s = q / 5, rem = q - s * 5;
    if (rem == 0) {              // L1(s): o = f*16+l15, K: c*9+py*3+px (18), k==18 -> b1
      int o = f * 16 + l15;
      if (kk < 18) {
        int c = (kk >= 9) ? 1 : 0;
        int rr = kk - c * 9;
        int py = rr / 3, px = rr - py * 3;
        int si = s >> 1, sj = s & 1;
        int di = py - si, dj = px - sj;
        if (di >= 0 && di < 2 && dj >= 0 && dj < 2)
          val = W1[((p * 128 + o) * 2 + c) * 4 + di * 2 + dj];
      } else if (kk == 18) {
        val = b1[p * 128 + o];
      }
    } else {                     // L2(s, kq=rem-1)
      int sk = s * 4 + rem - 1;
      int k2 = sk * 32 + kk;
      int o = f * 16 + l15, c = k2 & 127, si = k2 >> 7;
      val = W2[((p * 128 + o) * 128 + c) * 4 + si];
    }
  } else if (q < 24) {           // L3(kq=q-20)
    int k = (q - 20) * 32 + kk;
    int o = f * 16 + l15;
    val = W3[(p * 128 + o) * 128 + k];
  } else {                       // L4: f = nt*4+kq
    int k = (f & 3) * 32 + kk;
    int o = (f >> 2) * 16 + l15;
    val = W4[(p * 32 + o) * 128 + k];
  }
  wf[idx] = f2bf(val);
}

// ---------------- tower: counted-vmcnt 3-buffer phase pipeline ----------------
#define WAITV2() asm volatile("s_waitcnt vmcnt(2)" ::: "memory")
#define WAITV0() asm volatile("s_waitcnt vmcnt(0)" ::: "memory")
#define BARX()   { __builtin_amdgcn_s_barrier(); asm volatile("" ::: "memory"); }

__global__ __launch_bounds__(256, 3) void tower_kernel(
    const float* __restrict__ x,
    const float* __restrict__ b2v, const float* __restrict__ b3v,
    const float* __restrict__ b4v,
    const unsigned short* __restrict__ wf, float* __restrict__ part)
{
  __shared__ __align__(16) unsigned short ldsB[3 * 4096];   // 24KB, 3 x 8KB phase bufs
  __shared__ __align__(16) unsigned short xs[4][16 * 98];   // per-wave x rows (bf16)
  __shared__ __align__(16) unsigned short hb[4][16 * 128];  // per-wave inter-layer

  const int l = threadIdx.x & 63;
  const int wv = threadIdx.x >> 6;
  const int l15 = l & 15;
  const int g = l >> 4;

  int bid = blockIdx.x;
  int lin = (bid & 7) * 80 + (bid >> 3);     // XCD-contiguous
  int grp = lin / 128;
  int btile = lin - grp * 128;
  const int R0 = btile * 64 + wv * 16;

  unsigned short* xsw = xs[wv];
  unsigned short* hbw = hb[wv];

  int bufR = 0, bufS = 2;

#define STAGEQ(pn, qn)                                                          \
  {                                                                             \
    unsigned short* dst_ = ldsB + bufS * 4096;                                  \
    const unsigned short* src_ = wf + (((pn) * 25 + (qn)) * 8) * 512 + l * 8;   \
    gload_lds16(src_ + wv * 512, dst_ + wv * 512);                              \
    gload_lds16(src_ + (wv + 4) * 512, dst_ + (wv + 4) * 512);                  \
  }
#define ROT() { bufR = (bufR == 2) ? 0 : bufR + 1; bufS = (bufS == 2) ? 0 : bufS + 1; }

  // prologue: stage phases 0 and 1 into bufs 0,1 (no barrier needed yet)
  {
    int p0 = grp * PPG;
    unsigned short* dst0 = ldsB;
    const unsigned short* src0 = wf + ((p0 * 25 + 0) * 8) * 512 + l * 8;
    const unsigned short* src1 = wf + ((p0 * 25 + 1) * 8) * 512 + l * 8;
    gload_lds16(src0 + wv * 512, dst0 + wv * 512);
    gload_lds16(src0 + (wv + 4) * 512, dst0 + (wv + 4) * 512);
    gload_lds16(src1 + wv * 512, dst0 + 4096 + wv * 512);
    gload_lds16(src1 + (wv + 4) * 512, dst0 + 4096 + (wv + 4) * 512);
  }

  // fill xs (per-wave private, bf16)
  for (int idx = l; idx < 16 * 98; idx += 64)
    xsw[idx] = f2bf(x[(size_t)R0 * 98 + idx]);

  // per-lane K decode for L1 A-fragment
  int kbase[8]; int kmode[8];   // 0: zero, 1: xs, 2: const one
#pragma unroll
  for (int j = 0; j < 8; ++j) {
    int k = g * 8 + j;
    if (k < 18) {
      int c = (k >= 9) ? 1 : 0;
      int rr = k - c * 9;
      int py = rr / 3, px = rr - (rr / 3) * 3;
      kbase[j] = c * 49 + py * 7 + px;
      kmode[j] = 1;
    } else { kbase[j] = 0; kmode[j] = (k == 18) ? 2 : 0; }
  }

  const f32x4 zf = {0.f, 0.f, 0.f, 0.f};
  f32x4 facc0 = zf, facc1 = zf;

#define EPI_STORE(vals_t, colv)                                                  \
  {                                                                              \
    union { __hip_bfloat162 h; unsigned u; } ua_, ub_;                           \
    ua_.h = __float22bfloat162_rn(make_float2(vals_t[0], vals_t[1]));            \
    ub_.h = __float22bfloat162_rn(make_float2(vals_t[2], vals_t[3]));            \
    int r0_ = g * 4;                                                             \
    hbw[((r0_    ) * 128 + (colv)) ^ (((r0_    ) & 7) << 3)] = (unsigned short)(ua_.u); \
    hbw[((r0_ + 1) * 128 + (colv)) ^ (((r0_ + 1) & 7) << 3)] = (unsigned short)(ua_.u >> 16); \
    hbw[((r0_ + 2) * 128 + (colv)) ^ (((r0_ + 2) & 7) << 3)] = (unsigned short)(ub_.u); \
    hbw[((r0_ + 3) * 128 + (colv)) ^ (((r0_ + 3) & 7) << 3)] = (unsigned short)(ub_.u >> 16); \
  }

  for (int pp = 0; pp < PPG; ++pp) {
    const int p = grp * PPG + pp;
    const int y0 = p / 5;
    const int x0 = p - y0 * 5;
    const int poff = y0 * 7 + x0;

    bf16x8 a1;
#pragma unroll
    for (int j = 0; j < 8; ++j) {
      unsigned short v = 0;
      if (kmode[j] == 1) v = xsw[l15 * 98 + kbase[j] + poff];
      else if (kmode[j] == 2) v = 0x3F80;   // 1.0 bf16 (bias channel)
      a1[j] = (short)v;
    }

    f32x4 acc2[8];
#pragma unroll
    for (int t = 0; t < 8; ++t) acc2[t] = zf;

#pragma unroll
    for (int s = 0; s < 4; ++s) {
      // ---- phase q=5s : L1(s) ----
      WAITV2(); BARX();
      STAGEQ(p, 5 * s + 2);
      {
        const unsigned short* bbuf = ldsB + bufR * 4096;
        f32x4 c1[8];
        __builtin_amdgcn_s_setprio(1);
#pragma unroll
        for (int t = 0; t < 8; ++t) {
          bf16x8 bw = *(const bf16x8*)(bbuf + t * 512 + l * 8);
          c1[t] = mfma16(a1, bw, zf);
        }
        __builtin_amdgcn_s_setprio(0);
#pragma unroll
        for (int t = 0; t < 8; ++t) {
          float v[4];
#pragma unroll
          for (int r = 0; r < 4; ++r) v[r] = fmaxf(c1[t][r], 0.f);
          EPI_STORE(v, t * 16 + l15);
        }
      }
      ROT();

      // ---- phases q=5s+1+kq : L2(s,kq) ----
#pragma unroll
      for (int kq = 0; kq < 4; ++kq) {
        WAITV2(); BARX();
        STAGEQ(p, 5 * s + 3 + kq);                 // q+2, always within position
        {
          const unsigned short* bbuf = ldsB + bufR * 4096;
          bf16x8 a2 = *(const bf16x8*)&hbw[(l15 * 128 + (kq * 32 + g * 8)) ^ ((l15 & 7) << 3)];
          __builtin_amdgcn_s_setprio(1);
#pragma unroll
          for (int t = 0; t < 8; ++t) {
            bf16x8 bw = *(const bf16x8*)(bbuf + t * 512 + l * 8);
            acc2[t] = mfma16(a2, bw, acc2[t]);
          }
          __builtin_amdgcn_s_setprio(0);
          if (s == 3 && kq == 3) {
#pragma unroll
            for (int t = 0; t < 8; ++t) {
              float bias = b2v[p * 128 + t * 16 + l15];
              float v[4];
#pragma unroll
              for (int r = 0; r < 4; ++r) v[r] = fmaxf(acc2[t][r] + bias, 0.f);
              EPI_STORE(v, t * 16 + l15);
            }
          }
        }
        ROT();
      }
    }

    // ---- phases q=20..23 : L3(kq) ----
    f32x4 acc3[8];
#pragma unroll
    for (int t = 0; t < 8; ++t) acc3[t] = zf;
#pragma unroll
    for (int kq = 0; kq < 4; ++kq) {
      WAITV2(); BARX();
      if (kq < 3) { STAGEQ(p, 22 + kq); }
      else if (pp != PPG - 1) { STAGEQ(p + 1, 0); }
      {
        const unsigned short* bbuf = ldsB + bufR * 4096;
        bf16x8 a = *(const bf16x8*)&hbw[(l15 * 128 + (kq * 32 + g * 8)) ^ ((l15 & 7) << 3)];
        __builtin_amdgcn_s_setprio(1);
#pragma unroll
        for (int t = 0; t < 8; ++t) {
          bf16x8 bw = *(const bf16x8*)(bbuf + t * 512 + l * 8);
          acc3[t] = mfma16(a, bw, acc3[t]);
        }
        __builtin_amdgcn_s_setprio(0);
        if (kq == 3) {
#pragma unroll
          for (int t = 0; t < 8; ++t) {
            float bias = b3v[p * 128 + t * 16 + l15];
            float v[4];
#pragma unroll
            for (int r = 0; r < 4; ++r) v[r] = fmaxf(acc3[t][r] + bias, 0.f);
            EPI_STORE(v, t * 16 + l15);
          }
        }
      }
      ROT();
    }

    // ---- phase q=24 : L4 ----
    if (pp == PPG - 1) { WAITV0(); } else { WAITV2(); }
    BARX();
    if (pp != PPG - 1) { STAGEQ(p + 1, 1); }
    {
      const unsigned short* bbuf = ldsB + bufR * 4096;
      f32x4 c40 = zf, c41 = zf;
      __builtin_amdgcn_s_setprio(1);
#pragma unroll
      for (int kq = 0; kq < 4; ++kq) {
        bf16x8 a = *(const bf16x8*)&hbw[(l15 * 128 + (kq * 32 + g * 8)) ^ ((l15 & 7) << 3)];
        bf16x8 bw0 = *(const bf16x8*)(bbuf + kq * 512 + l * 8);
        bf16x8 bw1 = *(const bf16x8*)(bbuf + (4 + kq) * 512 + l * 8);
        c40 = mfma16(a, bw0, c40);
        c41 = mfma16(a, bw1, c41);
      }
      __builtin_amdgcn_s_setprio(0);
      float bias0 = b4v[p * 32 + l15];
      float bias1b = b4v[p * 32 + 16 + l15];
#pragma unroll
      for (int r = 0; r < 4; ++r) {
        float v0 = c40[r] + bias0;
        v0 = v0 < -1.f ? -1.f : (v0 > CMAXF ? CMAXF : v0);
        facc0[r] += v0;
        float v1 = c41[r] + bias1b;
        v1 = v1 < -1.f ? -1.f : (v1 > CMAXF ? CMAXF : v1);
        facc1[r] += v1;
      }
    }
    ROT();
  }
#undef STAGEQ
#undef ROT
#undef EPI_STORE

#pragma unroll
  for (int r = 0; r < 4; ++r) {
    int row = R0 + g * 4 + r;
    part[((size_t)grp * BATCH + row) * 32 + l15] = facc0[r];
    part[((size_t)grp * BATCH + row) * 32 + 16 + l15] = facc1[r];
  }
}

// ---------------- head: wave-per-2-rows, lane-per-output MLP ----------------
__global__ __launch_bounds__(256) void head_kernel(
    const float* __restrict__ part,
    const float* __restrict__ fc1w, const float* __restrict__ fc1b,
    const float* __restrict__ fc2w, const float* __restrict__ fc2b,
    const float* __restrict__ fc3w, const float* __restrict__ fc3b,
    float* __restrict__ out)
{
  const int lane = threadIdx.x & 63;
  const int o = lane & 31;
  const int half = lane >> 5;
  const int wave = threadIdx.x >> 6;
  const int row = blockIdx.x * 8 + wave * 2 + half;

  float feat = 0.f;
#pragma unroll
  for (int gi = 0; gi < NGRP; ++gi)
    feat += part[((size_t)gi * BATCH + row) * 32 + o];
  feat = feat < 0.f ? 0.f : (feat > CMAXF ? CMAXF : feat);

  float a = fc1b[o];
#pragma unroll
  for (int k = 0; k < 32; ++k)
    a += __shfl(feat, k, 32) * fc1w[o * 32 + k];
  a = a < 0.f ? 0.f : (a > CMAXF ? CMAXF : a);

  float b = fc2b[o];
#pragma unroll
  for (int k = 0; k < 32; ++k)
    b += __shfl(a, k, 32) * fc2w[o * 32 + k];
  b = b < 0.f ? 0.f : (b > CMAXF ? CMAXF : b);

  float c = b * fc3w[o];
#pragma unroll
  for (int m = 16; m >= 1; m >>= 1)
    c += __shfl_xor(c, m, 32);
  if (o == 0) out[row] = c + fc3b[0];
}

extern "C" void kernel_launch(void* const* d_in, const int* in_sizes, int n_in,
                              void* d_out, int out_size, void* d_ws, size_t ws_size,
                              hipStream_t stream) {
  const float* x    = (const float*)d_in[0];
  const float* W1   = (const float*)d_in[1];
  const float* b1   = (const float*)d_in[2];
  const float* W2   = (const float*)d_in[3];
  const float* b2   = (const float*)d_in[4];
  const float* W3   = (const float*)d_in[5];
  const float* b3   = (const float*)d_in[6];
  const float* W4   = (const float*)d_in[7];
  const float* b4   = (const float*)d_in[8];
  const float* fc1w = (const float*)d_in[9];
  const float* fc1b = (const float*)d_in[10];
  const float* fc2w = (const float*)d_in[11];
  const float* fc2b = (const float*)d_in[12];
  const float* fc3w = (const float*)d_in[13];
  const float* fc3b = (const float*)d_in[14];
  float* out = (float*)d_out;

  unsigned short* wf = (unsigned short*)d_ws;
  float* part = (float*)((char*)d_ws + PART_BYTE_OFF);

  prep_kernel<<<(WF_TOTAL + 255) / 256, 256, 0, stream>>>(W1, b1, W2, W3, W4, wf);
  tower_kernel<<<640, 256, 0, stream>>>(x, b2, b3, b4, wf, part);
  head_kernel<<<BATCH / 8, 256, 0, stream>>>(part, fc1w, fc1b, fc2w, fc2b, fc3w, fc3b, out);
}